// Round 17
// baseline (410.885 us; speedup 1.0000x reference)
//
#include <hip/hip_runtime.h>

#define NN 100000
#define NE 1600000
#define HH 32
#define CC 10
#define GG 64
#define NB 391
#define PBLK 100
#define ECH 16000
#define MTOT (NB * PBLK)
#define MSB ((MTOT + 255) / 256)

typedef _Float16 half8 __attribute__((ext_vector_type(8)));
typedef _Float16 half2v __attribute__((ext_vector_type(2)));
typedef float f32x4 __attribute__((ext_vector_type(4)));

__device__ __forceinline__ half2v bch(int v) { return __builtin_bit_cast(half2v, v); }

__global__ void zero_f(float* p, int n) {
    int i = blockIdx.x * 256 + threadIdx.x;
    if (i < n) p[i] = 0.0f;
}

__global__ void precompute_small(const float* __restrict__ fW, const float* __restrict__ fb,
                                 const float* __restrict__ W1, const float* __restrict__ b1,
                                 const float* __restrict__ W2, const float* __restrict__ b2,
                                 const float* __restrict__ g1W, float* __restrict__ tab) {
    int c = blockIdx.x;
    int k = threadIdx.x >> 5;
    int j = threadIdx.x & 31;
    float m = 0.f;
    for (int mm = 0; mm < 32; ++mm)
        m += W2[k * 32 + mm] * g1W[(3 + 32 * c + mm) * 32 + j];
    tab[2240 + c * 1024 + k * 32 + j] = m;

    if (k < 3) {
        float a = 0.f, b = 0.f;
        for (int i = 0; i < 32; ++i) {
            float w = fW[c * 96 + k * 32 + i];
            a += w * W1[i * 32 + j];
            b += w * W1[(32 + i) * 32 + j];
        }
        tab[c * 96 + k * 32 + j] = a;
        tab[960 + c * 96 + k * 32 + j] = b;
    } else if (k == 3) {
        float h = b1[j];
        for (int i = 0; i < 32; ++i)
            h += fb[c * 32 + i] * (W1[i * 32 + j] + W1[(32 + i) * 32 + j]);
        tab[1920 + c * 32 + j] = h;
    } else if (k == 4 && c == 0) {
        float t = 0.f;
        for (int cc2 = 0; cc2 < CC; ++cc2)
            for (int mm = 0; mm < 32; ++mm)
                t += b2[mm] * g1W[(3 + 32 * cc2 + mm) * 32 + j];
        tab[12480 + j] = t;
    }
}

// B-fragments of Mflat[320][32], plain fp16. 20 sets (kc 0..9, jtile 0..1).
__global__ void mfrag_kernel(const float* __restrict__ tab, _Float16* __restrict__ Mfrag) {
    int gid = blockIdx.x * 256 + threadIdx.x;   // [0, 1280)
    if (gid >= 1280) return;
    int set = gid >> 6, l = gid & 63;
    int kc = set >> 1, jt = set & 1;
    int j = jt * 16 + (l & 15);
    int kbase = kc * 32 + (l >> 4) * 8;
#pragma unroll
    for (int i = 0; i < 8; ++i)
        Mfrag[gid * 8 + i] = (_Float16)tab[2240 + (kbase + i) * 32 + j];
}

// ---- atomic-free CSR build ----
__global__ void bucket_hist(const int* __restrict__ ei, int* __restrict__ mat) {
    __shared__ int h[NB];
    int blk = blockIdx.x, tid = threadIdx.x;
    for (int i = tid; i < NB; i += 256) h[i] = 0;
    __syncthreads();
    int base = blk * ECH;
    for (int k = tid; k < ECH; k += 256)
        atomicAdd(&h[ei[NE + base + k] >> 8], 1);
    __syncthreads();
    for (int i = tid; i < NB; i += 256) mat[i * PBLK + blk] = h[i];
}

__global__ void scan_m1(const int* __restrict__ mat, int* __restrict__ msum) {
    __shared__ int sh[256];
    int b = blockIdx.x, t = threadIdx.x;
    int i = b * 256 + t;
    sh[t] = (i < MTOT) ? mat[i] : 0;
    __syncthreads();
    for (int off = 128; off > 0; off >>= 1) {
        if (t < off) sh[t] += sh[t + off];
        __syncthreads();
    }
    if (t == 0) msum[b] = sh[0];
}

__global__ void scan_m2(int* __restrict__ msum) {
    __shared__ int sh[256];
    int t = threadIdx.x;
    int v = (t < MSB) ? msum[t] : 0;
    sh[t] = v;
    __syncthreads();
    for (int off = 1; off < 256; off <<= 1) {
        int add = (t >= off) ? sh[t - off] : 0;
        __syncthreads();
        sh[t] += add;
        __syncthreads();
    }
    if (t < MSB) msum[t] = sh[t] - v;
}

__global__ void scan_m3(int* __restrict__ mat, const int* __restrict__ msum) {
    __shared__ int sh[256];
    int b = blockIdx.x, t = threadIdx.x;
    int i = b * 256 + t;
    int v = (i < MTOT) ? mat[i] : 0;
    sh[t] = v;
    __syncthreads();
    for (int off = 1; off < 256; off <<= 1) {
        int add = (t >= off) ? sh[t - off] : 0;
        __syncthreads();
        sh[t] += add;
        __syncthreads();
    }
    if (i < MTOT) mat[i] = sh[t] - v + msum[b];
}

__global__ void bucket_scatter(const int* __restrict__ ei, const int* __restrict__ mat,
                               unsigned int* __restrict__ part) {
    __shared__ int bas[NB];
    __shared__ int cur[NB];
    int blk = blockIdx.x, tid = threadIdx.x;
    for (int i = tid; i < NB; i += 256) { bas[i] = mat[i * PBLK + blk]; cur[i] = 0; }
    __syncthreads();
    int base = blk * ECH;
    for (int k = tid; k < ECH; k += 256) {
        int e = base + k;
        int r = ei[e];
        int c = ei[NE + e];
        int b = c >> 8;
        int local = atomicAdd(&cur[b], 1);
        part[bas[b] + local] = (unsigned)r | ((unsigned)(c & 255) << 24);
    }
}

__global__ void bucket_build(const unsigned int* __restrict__ part, const int* __restrict__ mat,
                             const float* __restrict__ x, int* __restrict__ csr_row,
                             int* __restrict__ ideg, int* __restrict__ offs,
                             float* __restrict__ dinv, float4* __restrict__ xpad,
                             uint4* __restrict__ xs) {
    __shared__ int lh[256];
    __shared__ int lex[256];
    __shared__ int cur[256];
    int b = blockIdx.x, tid = threadIdx.x;
    int ebase = mat[b * PBLK];
    int eend = (b == NB - 1) ? NE : mat[(b + 1) * PBLK];
    int m = eend - ebase;
    lh[tid] = 0;
    __syncthreads();
    for (int k = tid; k < m; k += 256) {
        unsigned v = part[ebase + k];
        atomicAdd(&lh[v >> 24], 1);
    }
    __syncthreads();
    int cnt = lh[tid];
    lex[tid] = cnt;
    __syncthreads();
    for (int off = 1; off < 256; off <<= 1) {
        int v = (tid >= off) ? lex[tid - off] : 0;
        __syncthreads();
        lex[tid] += v;
        __syncthreads();
    }
    int excl = lex[tid] - cnt;
    lex[tid] = excl;
    cur[tid] = 0;
    int n = b * 256 + tid;
    if (n < NN) {
        ideg[n] = cnt;
        offs[n] = ebase + excl;
        float di = rsqrtf((float)cnt + 1.0f);
        dinv[n] = di;
        float x0 = x[n * 3], x1 = x[n * 3 + 1], x2 = x[n * 3 + 2];
        xpad[n] = make_float4(x0, x1, x2, di);
        _Float16 hx = (_Float16)x0, hy = (_Float16)x1, hz = (_Float16)x2;
        half2v sx = {hx, hx}, sy = {hy, hy}, sz = {hz, hz};
        xs[n] = make_uint4(__builtin_bit_cast(unsigned int, sx),
                           __builtin_bit_cast(unsigned int, sy),
                           __builtin_bit_cast(unsigned int, sz), 0u);
    }
    if (b == 0 && tid == 0) offs[NN] = NE;
    __syncthreads();
    for (int k = tid; k < m; k += 256) {
        unsigned v = part[ebase + k];
        int cl = (int)(v >> 24);
        int r = (int)(v & 0x00FFFFFFu);
        int local = atomicAdd(&cur[cl], 1);
        csr_row[ebase + lex[cl] + local] = r;
    }
}

// Edge phase, packed fp16 with degree-specialized fully-unrolled inner blocks.
// Half-wave 0 takes even edges, half-wave 1 odd edges; broadcast via shfl of
// pre-packed splats. Validity via acc += u*mask (branch-free).
__global__ __launch_bounds__(256, 6) void edgeconv_fused(
    const uint4* __restrict__ xs, const int* __restrict__ offs,
    const int* __restrict__ csr_row, const float* __restrict__ tab,
    _Float16* __restrict__ aggh) {
    int lane = threadIdx.x & 63;
    int j = lane & 31;
    int half = lane >> 5;

    half2v A0[5], A1[5], A2[5], B0[5], B1[5], B2[5], hb[5];
#pragma unroll
    for (int p = 0; p < 5; ++p) {
        int c0 = 2 * p, c1 = 2 * p + 1;
        A0[p] = half2v{(_Float16)tab[c0 * 96 + j],        (_Float16)tab[c1 * 96 + j]};
        A1[p] = half2v{(_Float16)tab[c0 * 96 + 32 + j],   (_Float16)tab[c1 * 96 + 32 + j]};
        A2[p] = half2v{(_Float16)tab[c0 * 96 + 64 + j],   (_Float16)tab[c1 * 96 + 64 + j]};
        B0[p] = half2v{(_Float16)tab[960 + c0 * 96 + j],      (_Float16)tab[960 + c1 * 96 + j]};
        B1[p] = half2v{(_Float16)tab[960 + c0 * 96 + 32 + j], (_Float16)tab[960 + c1 * 96 + 32 + j]};
        B2[p] = half2v{(_Float16)tab[960 + c0 * 96 + 64 + j], (_Float16)tab[960 + c1 * 96 + 64 + j]};
        hb[p] = half2v{(_Float16)tab[1920 + c0 * 32 + j], (_Float16)tab[1920 + c1 * 32 + j]};
    }
    const half2v zero = half2v{(_Float16)0.f, (_Float16)0.f};
    const half2v one  = half2v{(_Float16)1.f, (_Float16)1.f};

    int wid = blockIdx.x * 4 + (threadIdx.x >> 6);
    const int wstride = gridDim.x * 4;

    for (int n = wid; n < NN; n += wstride) {
        uint4 qn = xs[n];
        half2v pxn = bch((int)qn.x), pyn = bch((int)qn.y), pzn = bch((int)qn.z);
        half2v va[5], acc[5];
        float accf[10];
#pragma unroll
        for (int p = 0; p < 5; ++p) {
            va[p] = hb[p] + pxn * B0[p] + pyn * B1[p] + pzn * B2[p];
            acc[p] = zero;
            accf[2 * p] = 0.f;
            accf[2 * p + 1] = 0.f;
        }
        int e0 = offs[n], e1 = offs[n + 1];
        int cnt = e1 - e0;
        int vcn = cnt - half;   // iter t valid iff 2t < vcn

        if (cnt <= 32) {
            int ee = e0 + (lane & 31);
            int r = (ee < e1) ? csr_row[ee] : 0;
            uint4 q = xs[r];
            if (cnt <= 16) {
#pragma unroll
                for (int t = 0; t < 8; ++t) {
                    int src = 2 * t + half;
                    half2v px = bch(__shfl((int)q.x, src, 64));
                    half2v py = bch(__shfl((int)q.y, src, 64));
                    half2v pz = bch(__shfl((int)q.z, src, 64));
                    half2v mk = (2 * t < vcn) ? one : zero;
#pragma unroll
                    for (int p = 0; p < 5; ++p) {
                        half2v u = va[p] + px * A0[p] + py * A1[p] + pz * A2[p];
                        u = __builtin_elementwise_max(u, zero);
                        acc[p] += u * mk;
                    }
                }
            } else {
#pragma unroll
                for (int t = 0; t < 8; ++t) {     // edges 0..15 all valid
                    int src = 2 * t + half;
                    half2v px = bch(__shfl((int)q.x, src, 64));
                    half2v py = bch(__shfl((int)q.y, src, 64));
                    half2v pz = bch(__shfl((int)q.z, src, 64));
#pragma unroll
                    for (int p = 0; p < 5; ++p) {
                        half2v u = va[p] + px * A0[p] + py * A1[p] + pz * A2[p];
                        u = __builtin_elementwise_max(u, zero);
                        acc[p] += u;
                    }
                }
#pragma unroll
                for (int p = 0; p < 5; ++p) {     // flush (bound fp16 accumulation)
                    accf[2 * p]     += (float)acc[p].x;
                    accf[2 * p + 1] += (float)acc[p].y;
                    acc[p] = zero;
                }
#pragma unroll
                for (int t = 8; t < 16; ++t) {
                    int src = 2 * t + half;
                    half2v px = bch(__shfl((int)q.x, src, 64));
                    half2v py = bch(__shfl((int)q.y, src, 64));
                    half2v pz = bch(__shfl((int)q.z, src, 64));
                    half2v mk = (2 * t < vcn) ? one : zero;
#pragma unroll
                    for (int p = 0; p < 5; ++p) {
                        half2v u = va[p] + px * A0[p] + py * A1[p] + pz * A2[p];
                        u = __builtin_elementwise_max(u, zero);
                        acc[p] += u * mk;
                    }
                }
            }
        } else {
            // rare (deg > 32): dynamic chunk loop
            for (int base = e0; base < e1; base += 64) {
                int ee = base + lane;
                int r = (ee < e1) ? csr_row[ee] : 0;
                uint4 q = xs[r];
                int c2 = e1 - base;
                if (c2 > 64) c2 = 64;
                int tfull = c2 >> 1;
                for (int t = 0; t < tfull; ++t) {
                    int src = 2 * t + half;
                    half2v px = bch(__shfl((int)q.x, src, 64));
                    half2v py = bch(__shfl((int)q.y, src, 64));
                    half2v pz = bch(__shfl((int)q.z, src, 64));
#pragma unroll
                    for (int p = 0; p < 5; ++p) {
                        half2v u = va[p] + px * A0[p] + py * A1[p] + pz * A2[p];
                        u = __builtin_elementwise_max(u, zero);
                        acc[p] += u;
                    }
                    if ((t & 7) == 7) {
#pragma unroll
                        for (int p = 0; p < 5; ++p) {
                            accf[2 * p]     += (float)acc[p].x;
                            accf[2 * p + 1] += (float)acc[p].y;
                            acc[p] = zero;
                        }
                    }
                }
                if (c2 & 1) {
                    int src = c2 - 1;
                    half2v px = bch(__shfl((int)q.x, src, 64));
                    half2v py = bch(__shfl((int)q.y, src, 64));
                    half2v pz = bch(__shfl((int)q.z, src, 64));
                    if (half == 0) {
#pragma unroll
                        for (int p = 0; p < 5; ++p) {
                            half2v u = va[p] + px * A0[p] + py * A1[p] + pz * A2[p];
                            u = __builtin_elementwise_max(u, zero);
                            acc[p] += u;
                        }
                    }
                }
#pragma unroll
                for (int p = 0; p < 5; ++p) {
                    accf[2 * p]     += (float)acc[p].x;
                    accf[2 * p + 1] += (float)acc[p].y;
                    acc[p] = zero;
                }
            }
        }
        // final flush + cross-half reduce (half0 even-edge sums, half1 odd)
#pragma unroll
        for (int p = 0; p < 5; ++p) {
            accf[2 * p]     += (float)acc[p].x;
            accf[2 * p + 1] += (float)acc[p].y;
        }
#pragma unroll
        for (int c = 0; c < 10; ++c) accf[c] += __shfl_xor(accf[c], 32, 64);
        _Float16* arow = aggh + (size_t)n * 320 + j;
#pragma unroll
        for (int i = 0; i < 5; ++i) {
            int c = half * 5 + i;
            arow[c * 32] = (_Float16)accf[c];
        }
    }
}

// Fold via MFMA (plain fp16, 2 MFMA/kc) + fused xw1-init; writes y1 = h*dinv fp16.
__global__ __launch_bounds__(256) void fold_mfma(
    const _Float16* __restrict__ aggh, const _Float16* __restrict__ MfragG,
    const float4* __restrict__ xpad, const int* __restrict__ ideg,
    const float* __restrict__ tab, const float* __restrict__ g1W,
    _Float16* __restrict__ y1) {
    __shared__ _Float16 Mf[10240];
    {
        const uint4* src = (const uint4*)MfragG;
        uint4* dst = (uint4*)Mf;
        for (int i = threadIdx.x; i < 1280; i += 256) dst[i] = src[i];
    }
    __syncthreads();

    int wave = blockIdx.x * 4 + (threadIdx.x >> 6);
    int lane = threadIdx.x & 63;
    int n0 = wave * 16;
    if (n0 >= NN) return;

    int m = lane & 15, q = lane >> 4;
    int arow_n = n0 + m;
    bool rowok = arow_n < NN;
    const _Float16* arow = aggh + (size_t)arow_n * 320 + q * 8;

    const half8* mf = (const half8*)Mf;
    f32x4 acc0 = {0.f, 0.f, 0.f, 0.f};
    f32x4 acc1 = {0.f, 0.f, 0.f, 0.f};

    for (int kc = 0; kc < 10; ++kc) {
        half8 a;
        if (rowok) a = *(const half8*)(arow + kc * 32);
        else {
#pragma unroll
            for (int i = 0; i < 8; ++i) a[i] = (_Float16)0.f;
        }
        half8 b0 = mf[(kc * 2 + 0) * 64 + lane];
        half8 b1 = mf[(kc * 2 + 1) * 64 + lane];
        acc0 = __builtin_amdgcn_mfma_f32_16x16x32_f16(a, b0, acc0, 0, 0, 0);
        acc1 = __builtin_amdgcn_mfma_f32_16x16x32_f16(a, b1, acc1, 0, 0, 0);
    }

    int jcol = lane & 15;
    float t0 = tab[12480 + jcol],      t1 = tab[12480 + 16 + jcol];
    float w00 = g1W[jcol],      w01 = g1W[32 + jcol],      w02 = g1W[64 + jcol];
    float w10 = g1W[16 + jcol], w11 = g1W[48 + jcol],      w12 = g1W[80 + jcol];
#pragma unroll
    for (int r = 0; r < 4; ++r) {
        int node = n0 + q * 4 + r;
        if (node < NN) {
            float4 xn = xpad[node];
            float dg = (float)ideg[node];
            float v0 = dg * t0 + xn.x * w00 + xn.y * w01 + xn.z * w02 + acc0[r];
            float v1 = dg * t1 + xn.x * w10 + xn.y * w11 + xn.z * w12 + acc1[r];
            y1[node * 32 + jcol]      = (_Float16)(v0 * xn.w);
            y1[node * 32 + 16 + jcol] = (_Float16)(v1 * xn.w);
        }
    }
}

// prop1 + fused xw2: 4 nodes/wave, 16 lanes/node, unroll-8 gathers.
__global__ __launch_bounds__(256, 8) void prop1_fused(
    const int* __restrict__ offs, const int* __restrict__ csr_row,
    const unsigned int* __restrict__ y1p, const float* __restrict__ dinv,
    const float* __restrict__ g1b, const float* __restrict__ g2W,
    unsigned int* __restrict__ y2p) {
    __shared__ float g2s[1024];
    for (int i = threadIdx.x; i < 1024; i += 256) g2s[i] = g2W[i];
    __syncthreads();

    int lane = threadIdx.x & 63;
    int l = lane & 15;
    int wid = blockIdx.x * 4 + (threadIdx.x >> 6);
    int n = wid * 4 + (lane >> 4);
    if (n >= NN) return;

    int e0 = offs[n], e1 = offs[n + 1];
    float sAl = 0.f, sAh = 0.f, sBl = 0.f, sBh = 0.f;
    int e = e0;
    for (; e + 7 < e1; e += 8) {
        int r[8];
#pragma unroll
        for (int u = 0; u < 8; ++u) r[u] = csr_row[e + u];
        half2v p[8];
#pragma unroll
        for (int u = 0; u < 8; ++u) p[u] = __builtin_bit_cast(half2v, y1p[r[u] * 16 + l]);
#pragma unroll
        for (int u = 0; u < 8; u += 2) {
            sAl += (float)p[u].x;     sAh += (float)p[u].y;
            sBl += (float)p[u + 1].x; sBh += (float)p[u + 1].y;
        }
    }
    for (; e < e1; ++e) {
        int r = csr_row[e];
        half2v p = __builtin_bit_cast(half2v, y1p[r * 16 + l]);
        sAl += (float)p.x; sAh += (float)p.y;
    }
    float di = dinv[n];
    half2v pn = __builtin_bit_cast(half2v, y1p[n * 16 + l]);
    float h1l = di * (sAl + sBl + (float)pn.x);
    float h1h = di * (sAh + sBh + (float)pn.y);
    float hl = fmaxf(h1l + g1b[2 * l], 0.f);
    float hh = fmaxf(h1h + g1b[2 * l + 1], 0.f);

    float al = 0.f, ah = 0.f;
    int base = lane & 48;
#pragma unroll
    for (int m = 0; m < 16; ++m) {
        float xl = __shfl(hl, base + m, 64);
        float xh2 = __shfl(hh, base + m, 64);
        al += xl * g2s[(2 * m) * 32 + 2 * l] + xh2 * g2s[(2 * m + 1) * 32 + 2 * l];
        ah += xl * g2s[(2 * m) * 32 + 2 * l + 1] + xh2 * g2s[(2 * m + 1) * 32 + 2 * l + 1];
    }
    half2v o = {(_Float16)(al * di), (_Float16)(ah * di)};
    y2p[n * 16 + l] = __builtin_bit_cast(unsigned int, o);
}

// prop2: same structure; h2 = di*(sum y2[r] + y2[n]); stored fp16 (pre-bias).
__global__ __launch_bounds__(256, 8) void prop2_plain(
    const int* __restrict__ offs, const int* __restrict__ csr_row,
    const unsigned int* __restrict__ y2p, const float* __restrict__ dinv,
    unsigned int* __restrict__ outp) {
    int lane = threadIdx.x & 63;
    int l = lane & 15;
    int wid = blockIdx.x * 4 + (threadIdx.x >> 6);
    int n = wid * 4 + (lane >> 4);
    if (n >= NN) return;

    int e0 = offs[n], e1 = offs[n + 1];
    float sAl = 0.f, sAh = 0.f, sBl = 0.f, sBh = 0.f;
    int e = e0;
    for (; e + 7 < e1; e += 8) {
        int r[8];
#pragma unroll
        for (int u = 0; u < 8; ++u) r[u] = csr_row[e + u];
        half2v p[8];
#pragma unroll
        for (int u = 0; u < 8; ++u) p[u] = __builtin_bit_cast(half2v, y2p[r[u] * 16 + l]);
#pragma unroll
        for (int u = 0; u < 8; u += 2) {
            sAl += (float)p[u].x;     sAh += (float)p[u].y;
            sBl += (float)p[u + 1].x; sBh += (float)p[u + 1].y;
        }
    }
    for (; e < e1; ++e) {
        int r = csr_row[e];
        half2v p = __builtin_bit_cast(half2v, y2p[r * 16 + l]);
        sAl += (float)p.x; sAh += (float)p.y;
    }
    float di = dinv[n];
    half2v pn = __builtin_bit_cast(half2v, y2p[n * 16 + l]);
    half2v o = {(_Float16)(di * (sAl + sBl + (float)pn.x)),
                (_Float16)(di * (sAh + sBh + (float)pn.y))};
    outp[n * 16 + l] = __builtin_bit_cast(unsigned int, o);
}

__global__ void pool_seg(const _Float16* __restrict__ h2, const float* __restrict__ g2b,
                         const int* __restrict__ batch, float* __restrict__ pooled,
                         float* __restrict__ counts) {
    int grp = threadIdx.x >> 5, j = threadIdx.x & 31;
    int base = (blockIdx.x * 8 + grp) * 64;
    if (base >= NN) return;
    float bj = g2b[j];
    float acc = 0.f, cnt = 0.f;
    int curg = -1;
    int lim = base + 64;
    if (lim > NN) lim = NN;
    for (int n = base; n < lim; ++n) {
        int g = batch[n];
        if (g != curg) {
            if (curg >= 0) {
                atomicAdd(&pooled[curg * 32 + j], acc);
                if (j == 0) atomicAdd(&counts[curg], cnt);
            }
            curg = g; acc = 0.f; cnt = 0.f;
        }
        acc += fmaxf((float)h2[n * 32 + j] + bj, 0.f);
        cnt += 1.f;
    }
    if (curg >= 0) {
        atomicAdd(&pooled[curg * 32 + j], acc);
        if (j == 0) atomicAdd(&counts[curg], cnt);
    }
}

__global__ void final_kernel(const float* __restrict__ pooled, const float* __restrict__ counts,
                             const float* __restrict__ clsW, const float* __restrict__ clsb,
                             float* __restrict__ out) {
    int tid = threadIdx.x;
    if (tid >= GG * CC) return;
    int g = tid / CC, cc = tid % CC;
    float inv = 1.0f / fmaxf(counts[g], 1.0f);
    float s = clsb[cc];
    for (int j = 0; j < 32; ++j) s += (pooled[g * 32 + j] * inv) * clsW[j * CC + cc];
    out[g * CC + cc] = s;
}

extern "C" void kernel_launch(void* const* d_in, const int* in_sizes, int n_in,
                              void* d_out, int out_size, void* d_ws, size_t ws_size,
                              hipStream_t stream) {
    const float* x     = (const float*)d_in[0];
    const int*   ei    = (const int*)d_in[1];
    const int*   batch = (const int*)d_in[2];
    const float* fW    = (const float*)d_in[3];
    const float* fb    = (const float*)d_in[4];
    const float* W1    = (const float*)d_in[5];
    const float* b1    = (const float*)d_in[6];
    const float* W2    = (const float*)d_in[7];
    const float* b2    = (const float*)d_in[8];
    const float* g1W   = (const float*)d_in[9];
    const float* g1b   = (const float*)d_in[10];
    const float* g2W   = (const float*)d_in[11];
    const float* g2b   = (const float*)d_in[12];
    const float* clsW  = (const float*)d_in[13];
    const float* clsb  = (const float*)d_in[14];
    float* out = (float*)d_out;

    float4*         xpad    = (float4*)d_ws;                          // 1.6 MB
    uint4*          xs      = (uint4*)(xpad + NN);                    // 1.6 MB (fp16 splats)
    _Float16*       aggh    = (_Float16*)(xs + NN);                   // 64 MB (full)
    unsigned int*   part    = (unsigned int*)aggh;                    // ALIAS: build-phase only
    int*            csr_row = (int*)(aggh + (size_t)NN * 320);        // 6.4 MB
    int*            mat     = (int*)(csr_row + NE);
    int*            msum    = mat + MTOT;
    int*            ideg    = msum + 256;
    int*            offs    = ideg + NN;
    float*          dinv    = (float*)(offs + NN + 1);
    float*          tab     = dinv + NN;
    _Float16*       Mfrag   = (_Float16*)(tab + 16384);               // 20 KB
    _Float16*       y1      = Mfrag + 10240;                          // 6.4 MB
    unsigned int*   y2p     = (unsigned int*)(y1 + (size_t)NN * 32);  // 6.4 MB
    unsigned int*   h2p     = y2p + (size_t)NN * 16;                  // 6.4 MB
    float*          pooled  = (float*)(h2p + (size_t)NN * 16);
    float*          counts  = pooled + GG * 32;

    const int propBlocks = (NN + 15) / 16;
    const int foldBlocks = ((NN + 15) / 16 + 3) / 4;

    zero_f<<<(GG * 33 + 255) / 256, 256, 0, stream>>>(pooled, GG * 33);
    precompute_small<<<10, 1024, 0, stream>>>(fW, fb, W1, b1, W2, b2, g1W, tab);
    mfrag_kernel<<<5, 256, 0, stream>>>(tab, Mfrag);

    bucket_hist<<<PBLK, 256, 0, stream>>>(ei, mat);
    scan_m1<<<MSB, 256, 0, stream>>>(mat, msum);
    scan_m2<<<1, 256, 0, stream>>>(msum);
    scan_m3<<<MSB, 256, 0, stream>>>(mat, msum);
    bucket_scatter<<<PBLK, 256, 0, stream>>>(ei, mat, part);
    bucket_build<<<NB, 256, 0, stream>>>(part, mat, x, csr_row, ideg, offs, dinv, xpad, xs);

    edgeconv_fused<<<2048, 256, 0, stream>>>(xs, offs, csr_row, tab, aggh);
    fold_mfma<<<foldBlocks, 256, 0, stream>>>(aggh, Mfrag, xpad, ideg, tab, g1W, y1);

    prop1_fused<<<propBlocks, 256, 0, stream>>>(offs, csr_row, (const unsigned int*)y1,
                                                dinv, g1b, g2W, y2p);
    prop2_plain<<<propBlocks, 256, 0, stream>>>(offs, csr_row, y2p, dinv, h2p);
    pool_seg<<<(NN + 511) / 512, 256, 0, stream>>>((const _Float16*)h2p, g2b, batch,
                                                   pooled, counts);
    final_kernel<<<1, 640, 0, stream>>>(pooled, counts, clsW, clsb, out);
}

// Round 18
// 379.554 us; speedup vs baseline: 1.0825x; 1.0825x over previous
//
#include <hip/hip_runtime.h>

#define NN 100000
#define NE 1600000
#define HH 32
#define CC 10
#define GG 64
#define NB 391
#define PBLK 100
#define ECH 16000
#define MTOT (NB * PBLK)
#define MSB ((MTOT + 255) / 256)

typedef _Float16 half8 __attribute__((ext_vector_type(8)));
typedef _Float16 half2v __attribute__((ext_vector_type(2)));
typedef float f32x4 __attribute__((ext_vector_type(4)));

__device__ __forceinline__ half2v bch(int v) { return __builtin_bit_cast(half2v, v); }

__global__ void zero_f(float* p, int n) {
    int i = blockIdx.x * 256 + threadIdx.x;
    if (i < n) p[i] = 0.0f;
}

__global__ void precompute_small(const float* __restrict__ fW, const float* __restrict__ fb,
                                 const float* __restrict__ W1, const float* __restrict__ b1,
                                 const float* __restrict__ W2, const float* __restrict__ b2,
                                 const float* __restrict__ g1W, float* __restrict__ tab) {
    int c = blockIdx.x;
    int k = threadIdx.x >> 5;
    int j = threadIdx.x & 31;
    float m = 0.f;
    for (int mm = 0; mm < 32; ++mm)
        m += W2[k * 32 + mm] * g1W[(3 + 32 * c + mm) * 32 + j];
    tab[2240 + c * 1024 + k * 32 + j] = m;

    if (k < 3) {
        float a = 0.f, b = 0.f;
        for (int i = 0; i < 32; ++i) {
            float w = fW[c * 96 + k * 32 + i];
            a += w * W1[i * 32 + j];
            b += w * W1[(32 + i) * 32 + j];
        }
        tab[c * 96 + k * 32 + j] = a;
        tab[960 + c * 96 + k * 32 + j] = b;
    } else if (k == 3) {
        float h = b1[j];
        for (int i = 0; i < 32; ++i)
            h += fb[c * 32 + i] * (W1[i * 32 + j] + W1[(32 + i) * 32 + j]);
        tab[1920 + c * 32 + j] = h;
    } else if (k == 4 && c == 0) {
        float t = 0.f;
        for (int cc2 = 0; cc2 < CC; ++cc2)
            for (int mm = 0; mm < 32; ++mm)
                t += b2[mm] * g1W[(3 + 32 * cc2 + mm) * 32 + j];
        tab[12480 + j] = t;
    }
}

// B-fragments of Mflat[320][32], plain fp16. 20 sets (kc 0..9, jtile 0..1).
__global__ void mfrag_kernel(const float* __restrict__ tab, _Float16* __restrict__ Mfrag) {
    int gid = blockIdx.x * 256 + threadIdx.x;   // [0, 1280)
    if (gid >= 1280) return;
    int set = gid >> 6, l = gid & 63;
    int kc = set >> 1, jt = set & 1;
    int j = jt * 16 + (l & 15);
    int kbase = kc * 32 + (l >> 4) * 8;
#pragma unroll
    for (int i = 0; i < 8; ++i)
        Mfrag[gid * 8 + i] = (_Float16)tab[2240 + (kbase + i) * 32 + j];
}

// ---- atomic-free CSR build ----
__global__ void bucket_hist(const int* __restrict__ ei, int* __restrict__ mat) {
    __shared__ int h[NB];
    int blk = blockIdx.x, tid = threadIdx.x;
    for (int i = tid; i < NB; i += 256) h[i] = 0;
    __syncthreads();
    int base = blk * ECH;
    for (int k = tid; k < ECH; k += 256)
        atomicAdd(&h[ei[NE + base + k] >> 8], 1);
    __syncthreads();
    for (int i = tid; i < NB; i += 256) mat[i * PBLK + blk] = h[i];
}

__global__ void scan_m1(const int* __restrict__ mat, int* __restrict__ msum) {
    __shared__ int sh[256];
    int b = blockIdx.x, t = threadIdx.x;
    int i = b * 256 + t;
    sh[t] = (i < MTOT) ? mat[i] : 0;
    __syncthreads();
    for (int off = 128; off > 0; off >>= 1) {
        if (t < off) sh[t] += sh[t + off];
        __syncthreads();
    }
    if (t == 0) msum[b] = sh[0];
}

__global__ void scan_m2(int* __restrict__ msum) {
    __shared__ int sh[256];
    int t = threadIdx.x;
    int v = (t < MSB) ? msum[t] : 0;
    sh[t] = v;
    __syncthreads();
    for (int off = 1; off < 256; off <<= 1) {
        int add = (t >= off) ? sh[t - off] : 0;
        __syncthreads();
        sh[t] += add;
        __syncthreads();
    }
    if (t < MSB) msum[t] = sh[t] - v;
}

__global__ void scan_m3(int* __restrict__ mat, const int* __restrict__ msum) {
    __shared__ int sh[256];
    int b = blockIdx.x, t = threadIdx.x;
    int i = b * 256 + t;
    int v = (i < MTOT) ? mat[i] : 0;
    sh[t] = v;
    __syncthreads();
    for (int off = 1; off < 256; off <<= 1) {
        int add = (t >= off) ? sh[t - off] : 0;
        __syncthreads();
        sh[t] += add;
        __syncthreads();
    }
    if (i < MTOT) mat[i] = sh[t] - v + msum[b];
}

__global__ void bucket_scatter(const int* __restrict__ ei, const int* __restrict__ mat,
                               unsigned int* __restrict__ part) {
    __shared__ int bas[NB];
    __shared__ int cur[NB];
    int blk = blockIdx.x, tid = threadIdx.x;
    for (int i = tid; i < NB; i += 256) { bas[i] = mat[i * PBLK + blk]; cur[i] = 0; }
    __syncthreads();
    int base = blk * ECH;
    for (int k = tid; k < ECH; k += 256) {
        int e = base + k;
        int r = ei[e];
        int c = ei[NE + e];
        int b = c >> 8;
        int local = atomicAdd(&cur[b], 1);
        part[bas[b] + local] = (unsigned)r | ((unsigned)(c & 255) << 24);
    }
}

__global__ void bucket_build(const unsigned int* __restrict__ part, const int* __restrict__ mat,
                             const float* __restrict__ x, int* __restrict__ csr_row,
                             int* __restrict__ ideg, int* __restrict__ offs,
                             float* __restrict__ dinv, float4* __restrict__ xpad,
                             uint4* __restrict__ xs) {
    __shared__ int lh[256];
    __shared__ int lex[256];
    __shared__ int cur[256];
    int b = blockIdx.x, tid = threadIdx.x;
    int ebase = mat[b * PBLK];
    int eend = (b == NB - 1) ? NE : mat[(b + 1) * PBLK];
    int m = eend - ebase;
    lh[tid] = 0;
    __syncthreads();
    for (int k = tid; k < m; k += 256) {
        unsigned v = part[ebase + k];
        atomicAdd(&lh[v >> 24], 1);
    }
    __syncthreads();
    int cnt = lh[tid];
    lex[tid] = cnt;
    __syncthreads();
    for (int off = 1; off < 256; off <<= 1) {
        int v = (tid >= off) ? lex[tid - off] : 0;
        __syncthreads();
        lex[tid] += v;
        __syncthreads();
    }
    int excl = lex[tid] - cnt;
    lex[tid] = excl;
    cur[tid] = 0;
    int n = b * 256 + tid;
    if (n < NN) {
        ideg[n] = cnt;
        offs[n] = ebase + excl;
        float di = rsqrtf((float)cnt + 1.0f);
        dinv[n] = di;
        float x0 = x[n * 3], x1 = x[n * 3 + 1], x2 = x[n * 3 + 2];
        xpad[n] = make_float4(x0, x1, x2, di);
        _Float16 hx = (_Float16)x0, hy = (_Float16)x1, hz = (_Float16)x2;
        half2v sx = {hx, hx}, sy = {hy, hy}, sz = {hz, hz};
        xs[n] = make_uint4(__builtin_bit_cast(unsigned int, sx),
                           __builtin_bit_cast(unsigned int, sy),
                           __builtin_bit_cast(unsigned int, sz), 0u);
    }
    if (b == 0 && tid == 0) offs[NN] = NE;
    __syncthreads();
    for (int k = tid; k < m; k += 256) {
        unsigned v = part[ebase + k];
        int cl = (int)(v >> 24);
        int r = (int)(v & 0x00FFFFFFu);
        int local = atomicAdd(&cur[cl], 1);
        csr_row[ebase + lex[cl] + local] = r;
    }
}

// Edge phase, packed fp16; dynamic loop with unrolled groups-of-4 valid
// iterations (work strictly proportional to degree; no masks in the bulk).
__global__ __launch_bounds__(256, 6) void edgeconv_fused(
    const uint4* __restrict__ xs, const int* __restrict__ offs,
    const int* __restrict__ csr_row, const float* __restrict__ tab,
    _Float16* __restrict__ aggh) {
    int lane = threadIdx.x & 63;
    int j = lane & 31;
    int half = lane >> 5;

    half2v A0[5], A1[5], A2[5], B0[5], B1[5], B2[5], hb[5];
#pragma unroll
    for (int p = 0; p < 5; ++p) {
        int c0 = 2 * p, c1 = 2 * p + 1;
        A0[p] = half2v{(_Float16)tab[c0 * 96 + j],        (_Float16)tab[c1 * 96 + j]};
        A1[p] = half2v{(_Float16)tab[c0 * 96 + 32 + j],   (_Float16)tab[c1 * 96 + 32 + j]};
        A2[p] = half2v{(_Float16)tab[c0 * 96 + 64 + j],   (_Float16)tab[c1 * 96 + 64 + j]};
        B0[p] = half2v{(_Float16)tab[960 + c0 * 96 + j],      (_Float16)tab[960 + c1 * 96 + j]};
        B1[p] = half2v{(_Float16)tab[960 + c0 * 96 + 32 + j], (_Float16)tab[960 + c1 * 96 + 32 + j]};
        B2[p] = half2v{(_Float16)tab[960 + c0 * 96 + 64 + j], (_Float16)tab[960 + c1 * 96 + 64 + j]};
        hb[p] = half2v{(_Float16)tab[1920 + c0 * 32 + j], (_Float16)tab[1920 + c1 * 32 + j]};
    }
    const half2v zero = half2v{(_Float16)0.f, (_Float16)0.f};

    int wid = blockIdx.x * 4 + (threadIdx.x >> 6);
    const int wstride = gridDim.x * 4;

    for (int n = wid; n < NN; n += wstride) {
        uint4 qn = xs[n];
        half2v pxn = bch((int)qn.x), pyn = bch((int)qn.y), pzn = bch((int)qn.z);
        half2v va[5], acc[5];
        float accf[10];
#pragma unroll
        for (int p = 0; p < 5; ++p) {
            va[p] = hb[p] + pxn * B0[p] + pyn * B1[p] + pzn * B2[p];
            acc[p] = zero;
            accf[2 * p] = 0.f;
            accf[2 * p + 1] = 0.f;
        }
        int e0 = offs[n], e1 = offs[n + 1];
        for (int base = e0; base < e1; base += 64) {
            int ee = base + lane;
            int r = (ee < e1) ? csr_row[ee] : 0;
            uint4 q = xs[r];
            int c2 = e1 - base;
            if (c2 > 64) c2 = 64;
            int tfull = c2 >> 1;
            int t = 0;
            // groups of 4 fully-valid pair-iterations, flush each group
            for (; t + 4 <= tfull; t += 4) {
#pragma unroll
                for (int u = 0; u < 4; ++u) {
                    int src = 2 * (t + u) + half;
                    half2v px = bch(__shfl((int)q.x, src, 64));
                    half2v py = bch(__shfl((int)q.y, src, 64));
                    half2v pz = bch(__shfl((int)q.z, src, 64));
#pragma unroll
                    for (int p = 0; p < 5; ++p) {
                        half2v v = va[p] + px * A0[p] + py * A1[p] + pz * A2[p];
                        v = __builtin_elementwise_max(v, zero);
                        acc[p] += v;
                    }
                }
#pragma unroll
                for (int p = 0; p < 5; ++p) {
                    accf[2 * p]     += (float)acc[p].x;
                    accf[2 * p + 1] += (float)acc[p].y;
                    acc[p] = zero;
                }
            }
            // remainder 0..3 pair-iterations
            for (; t < tfull; ++t) {
                int src = 2 * t + half;
                half2v px = bch(__shfl((int)q.x, src, 64));
                half2v py = bch(__shfl((int)q.y, src, 64));
                half2v pz = bch(__shfl((int)q.z, src, 64));
#pragma unroll
                for (int p = 0; p < 5; ++p) {
                    half2v v = va[p] + px * A0[p] + py * A1[p] + pz * A2[p];
                    v = __builtin_elementwise_max(v, zero);
                    acc[p] += v;
                }
            }
            // odd final edge (half 0 only)
            if (c2 & 1) {
                int src = c2 - 1;
                half2v px = bch(__shfl((int)q.x, src, 64));
                half2v py = bch(__shfl((int)q.y, src, 64));
                half2v pz = bch(__shfl((int)q.z, src, 64));
                if (half == 0) {
#pragma unroll
                    for (int p = 0; p < 5; ++p) {
                        half2v v = va[p] + px * A0[p] + py * A1[p] + pz * A2[p];
                        v = __builtin_elementwise_max(v, zero);
                        acc[p] += v;
                    }
                }
            }
#pragma unroll
            for (int p = 0; p < 5; ++p) {
                accf[2 * p]     += (float)acc[p].x;
                accf[2 * p + 1] += (float)acc[p].y;
                acc[p] = zero;
            }
        }
        // cross-half reduce (half0 even-edge sums, half1 odd-edge sums)
#pragma unroll
        for (int c = 0; c < 10; ++c) accf[c] += __shfl_xor(accf[c], 32, 64);
        _Float16* arow = aggh + (size_t)n * 320 + j;
#pragma unroll
        for (int i = 0; i < 5; ++i) {
            int c = half * 5 + i;
            arow[c * 32] = (_Float16)accf[c];
        }
    }
}

// Fold via MFMA (plain fp16, 2 MFMA/kc) + fused xw1-init; writes y1 = h*dinv fp16.
__global__ __launch_bounds__(256) void fold_mfma(
    const _Float16* __restrict__ aggh, const _Float16* __restrict__ MfragG,
    const float4* __restrict__ xpad, const int* __restrict__ ideg,
    const float* __restrict__ tab, const float* __restrict__ g1W,
    _Float16* __restrict__ y1) {
    __shared__ _Float16 Mf[10240];
    {
        const uint4* src = (const uint4*)MfragG;
        uint4* dst = (uint4*)Mf;
        for (int i = threadIdx.x; i < 1280; i += 256) dst[i] = src[i];
    }
    __syncthreads();

    int wave = blockIdx.x * 4 + (threadIdx.x >> 6);
    int lane = threadIdx.x & 63;
    int n0 = wave * 16;
    if (n0 >= NN) return;

    int m = lane & 15, q = lane >> 4;
    int arow_n = n0 + m;
    bool rowok = arow_n < NN;
    const _Float16* arow = aggh + (size_t)arow_n * 320 + q * 8;

    const half8* mf = (const half8*)Mf;
    f32x4 acc0 = {0.f, 0.f, 0.f, 0.f};
    f32x4 acc1 = {0.f, 0.f, 0.f, 0.f};

    for (int kc = 0; kc < 10; ++kc) {
        half8 a;
        if (rowok) a = *(const half8*)(arow + kc * 32);
        else {
#pragma unroll
            for (int i = 0; i < 8; ++i) a[i] = (_Float16)0.f;
        }
        half8 b0 = mf[(kc * 2 + 0) * 64 + lane];
        half8 b1 = mf[(kc * 2 + 1) * 64 + lane];
        acc0 = __builtin_amdgcn_mfma_f32_16x16x32_f16(a, b0, acc0, 0, 0, 0);
        acc1 = __builtin_amdgcn_mfma_f32_16x16x32_f16(a, b1, acc1, 0, 0, 0);
    }

    int jcol = lane & 15;
    float t0 = tab[12480 + jcol],      t1 = tab[12480 + 16 + jcol];
    float w00 = g1W[jcol],      w01 = g1W[32 + jcol],      w02 = g1W[64 + jcol];
    float w10 = g1W[16 + jcol], w11 = g1W[48 + jcol],      w12 = g1W[80 + jcol];
#pragma unroll
    for (int r = 0; r < 4; ++r) {
        int node = n0 + q * 4 + r;
        if (node < NN) {
            float4 xn = xpad[node];
            float dg = (float)ideg[node];
            float v0 = dg * t0 + xn.x * w00 + xn.y * w01 + xn.z * w02 + acc0[r];
            float v1 = dg * t1 + xn.x * w10 + xn.y * w11 + xn.z * w12 + acc1[r];
            y1[node * 32 + jcol]      = (_Float16)(v0 * xn.w);
            y1[node * 32 + 16 + jcol] = (_Float16)(v1 * xn.w);
        }
    }
}

// prop1 + fused xw2: 4 nodes/wave, 16 lanes/node, unroll-8 + 4/2/1 ladder.
__global__ __launch_bounds__(256, 8) void prop1_fused(
    const int* __restrict__ offs, const int* __restrict__ csr_row,
    const unsigned int* __restrict__ y1p, const float* __restrict__ dinv,
    const float* __restrict__ g1b, const float* __restrict__ g2W,
    unsigned int* __restrict__ y2p) {
    __shared__ float g2s[1024];
    for (int i = threadIdx.x; i < 1024; i += 256) g2s[i] = g2W[i];
    __syncthreads();

    int lane = threadIdx.x & 63;
    int l = lane & 15;
    int wid = blockIdx.x * 4 + (threadIdx.x >> 6);
    int n = wid * 4 + (lane >> 4);
    if (n >= NN) return;

    int e0 = offs[n], e1 = offs[n + 1];
    float sAl = 0.f, sAh = 0.f, sBl = 0.f, sBh = 0.f;
    int e = e0;
    for (; e + 7 < e1; e += 8) {
        int r[8];
#pragma unroll
        for (int u = 0; u < 8; ++u) r[u] = csr_row[e + u];
        half2v p[8];
#pragma unroll
        for (int u = 0; u < 8; ++u) p[u] = __builtin_bit_cast(half2v, y1p[r[u] * 16 + l]);
#pragma unroll
        for (int u = 0; u < 8; u += 2) {
            sAl += (float)p[u].x;     sAh += (float)p[u].y;
            sBl += (float)p[u + 1].x; sBh += (float)p[u + 1].y;
        }
    }
    if (e + 3 < e1) {
        int r[4];
#pragma unroll
        for (int u = 0; u < 4; ++u) r[u] = csr_row[e + u];
        half2v p[4];
#pragma unroll
        for (int u = 0; u < 4; ++u) p[u] = __builtin_bit_cast(half2v, y1p[r[u] * 16 + l]);
        sAl += (float)p[0].x + (float)p[2].x; sAh += (float)p[0].y + (float)p[2].y;
        sBl += (float)p[1].x + (float)p[3].x; sBh += (float)p[1].y + (float)p[3].y;
        e += 4;
    }
    if (e + 1 < e1) {
        int r0 = csr_row[e], r1 = csr_row[e + 1];
        half2v p0 = __builtin_bit_cast(half2v, y1p[r0 * 16 + l]);
        half2v p1 = __builtin_bit_cast(half2v, y1p[r1 * 16 + l]);
        sAl += (float)p0.x; sAh += (float)p0.y;
        sBl += (float)p1.x; sBh += (float)p1.y;
        e += 2;
    }
    if (e < e1) {
        int r = csr_row[e];
        half2v p = __builtin_bit_cast(half2v, y1p[r * 16 + l]);
        sAl += (float)p.x; sAh += (float)p.y;
    }
    float di = dinv[n];
    half2v pn = __builtin_bit_cast(half2v, y1p[n * 16 + l]);
    float h1l = di * (sAl + sBl + (float)pn.x);
    float h1h = di * (sAh + sBh + (float)pn.y);
    float hl = fmaxf(h1l + g1b[2 * l], 0.f);
    float hh = fmaxf(h1h + g1b[2 * l + 1], 0.f);

    float al = 0.f, ah = 0.f;
    int base = lane & 48;
#pragma unroll
    for (int m = 0; m < 16; ++m) {
        float xl = __shfl(hl, base + m, 64);
        float xh2 = __shfl(hh, base + m, 64);
        al += xl * g2s[(2 * m) * 32 + 2 * l] + xh2 * g2s[(2 * m + 1) * 32 + 2 * l];
        ah += xl * g2s[(2 * m) * 32 + 2 * l + 1] + xh2 * g2s[(2 * m + 1) * 32 + 2 * l + 1];
    }
    half2v o = {(_Float16)(al * di), (_Float16)(ah * di)};
    y2p[n * 16 + l] = __builtin_bit_cast(unsigned int, o);
}

// prop2: same structure; h2 = di*(sum y2[r] + y2[n]); stored fp16 (pre-bias).
__global__ __launch_bounds__(256, 8) void prop2_plain(
    const int* __restrict__ offs, const int* __restrict__ csr_row,
    const unsigned int* __restrict__ y2p, const float* __restrict__ dinv,
    unsigned int* __restrict__ outp) {
    int lane = threadIdx.x & 63;
    int l = lane & 15;
    int wid = blockIdx.x * 4 + (threadIdx.x >> 6);
    int n = wid * 4 + (lane >> 4);
    if (n >= NN) return;

    int e0 = offs[n], e1 = offs[n + 1];
    float sAl = 0.f, sAh = 0.f, sBl = 0.f, sBh = 0.f;
    int e = e0;
    for (; e + 7 < e1; e += 8) {
        int r[8];
#pragma unroll
        for (int u = 0; u < 8; ++u) r[u] = csr_row[e + u];
        half2v p[8];
#pragma unroll
        for (int u = 0; u < 8; ++u) p[u] = __builtin_bit_cast(half2v, y2p[r[u] * 16 + l]);
#pragma unroll
        for (int u = 0; u < 8; u += 2) {
            sAl += (float)p[u].x;     sAh += (float)p[u].y;
            sBl += (float)p[u + 1].x; sBh += (float)p[u + 1].y;
        }
    }
    if (e + 3 < e1) {
        int r[4];
#pragma unroll
        for (int u = 0; u < 4; ++u) r[u] = csr_row[e + u];
        half2v p[4];
#pragma unroll
        for (int u = 0; u < 4; ++u) p[u] = __builtin_bit_cast(half2v, y2p[r[u] * 16 + l]);
        sAl += (float)p[0].x + (float)p[2].x; sAh += (float)p[0].y + (float)p[2].y;
        sBl += (float)p[1].x + (float)p[3].x; sBh += (float)p[1].y + (float)p[3].y;
        e += 4;
    }
    if (e + 1 < e1) {
        int r0 = csr_row[e], r1 = csr_row[e + 1];
        half2v p0 = __builtin_bit_cast(half2v, y2p[r0 * 16 + l]);
        half2v p1 = __builtin_bit_cast(half2v, y2p[r1 * 16 + l]);
        sAl += (float)p0.x; sAh += (float)p0.y;
        sBl += (float)p1.x; sBh += (float)p1.y;
        e += 2;
    }
    if (e < e1) {
        int r = csr_row[e];
        half2v p = __builtin_bit_cast(half2v, y2p[r * 16 + l]);
        sAl += (float)p.x; sAh += (float)p.y;
    }
    float di = dinv[n];
    half2v pn = __builtin_bit_cast(half2v, y2p[n * 16 + l]);
    half2v o = {(_Float16)(di * (sAl + sBl + (float)pn.x)),
                (_Float16)(di * (sAh + sBh + (float)pn.y))};
    outp[n * 16 + l] = __builtin_bit_cast(unsigned int, o);
}

__global__ void pool_seg(const _Float16* __restrict__ h2, const float* __restrict__ g2b,
                         const int* __restrict__ batch, float* __restrict__ pooled,
                         float* __restrict__ counts) {
    int grp = threadIdx.x >> 5, j = threadIdx.x & 31;
    int base = (blockIdx.x * 8 + grp) * 64;
    if (base >= NN) return;
    float bj = g2b[j];
    float acc = 0.f, cnt = 0.f;
    int curg = -1;
    int lim = base + 64;
    if (lim > NN) lim = NN;
    for (int n = base; n < lim; ++n) {
        int g = batch[n];
        if (g != curg) {
            if (curg >= 0) {
                atomicAdd(&pooled[curg * 32 + j], acc);
                if (j == 0) atomicAdd(&counts[curg], cnt);
            }
            curg = g; acc = 0.f; cnt = 0.f;
        }
        acc += fmaxf((float)h2[n * 32 + j] + bj, 0.f);
        cnt += 1.f;
    }
    if (curg >= 0) {
        atomicAdd(&pooled[curg * 32 + j], acc);
        if (j == 0) atomicAdd(&counts[curg], cnt);
    }
}

__global__ void final_kernel(const float* __restrict__ pooled, const float* __restrict__ counts,
                             const float* __restrict__ clsW, const float* __restrict__ clsb,
                             float* __restrict__ out) {
    int tid = threadIdx.x;
    if (tid >= GG * CC) return;
    int g = tid / CC, cc = tid % CC;
    float inv = 1.0f / fmaxf(counts[g], 1.0f);
    float s = clsb[cc];
    for (int j = 0; j < 32; ++j) s += (pooled[g * 32 + j] * inv) * clsW[j * CC + cc];
    out[g * CC + cc] = s;
}

extern "C" void kernel_launch(void* const* d_in, const int* in_sizes, int n_in,
                              void* d_out, int out_size, void* d_ws, size_t ws_size,
                              hipStream_t stream) {
    const float* x     = (const float*)d_in[0];
    const int*   ei    = (const int*)d_in[1];
    const int*   batch = (const int*)d_in[2];
    const float* fW    = (const float*)d_in[3];
    const float* fb    = (const float*)d_in[4];
    const float* W1    = (const float*)d_in[5];
    const float* b1    = (const float*)d_in[6];
    const float* W2    = (const float*)d_in[7];
    const float* b2    = (const float*)d_in[8];
    const float* g1W   = (const float*)d_in[9];
    const float* g1b   = (const float*)d_in[10];
    const float* g2W   = (const float*)d_in[11];
    const float* g2b   = (const float*)d_in[12];
    const float* clsW  = (const float*)d_in[13];
    const float* clsb  = (const float*)d_in[14];
    float* out = (float*)d_out;

    float4*         xpad    = (float4*)d_ws;                          // 1.6 MB
    uint4*          xs      = (uint4*)(xpad + NN);                    // 1.6 MB (fp16 splats)
    _Float16*       aggh    = (_Float16*)(xs + NN);                   // 64 MB (full)
    unsigned int*   part    = (unsigned int*)aggh;                    // ALIAS: build-phase only
    int*            csr_row = (int*)(aggh + (size_t)NN * 320);        // 6.4 MB
    int*            mat     = (int*)(csr_row + NE);
    int*            msum    = mat + MTOT;
    int*            ideg    = msum + 256;
    int*            offs    = ideg + NN;
    float*          dinv    = (float*)(offs + NN + 1);
    float*          tab     = dinv + NN;
    _Float16*       Mfrag   = (_Float16*)(tab + 16384);               // 20 KB
    _Float16*       y1      = Mfrag + 10240;                          // 6.4 MB
    unsigned int*   y2p     = (unsigned int*)(y1 + (size_t)NN * 32);  // 6.4 MB
    unsigned int*   h2p     = y2p + (size_t)NN * 16;                  // 6.4 MB
    float*          pooled  = (float*)(h2p + (size_t)NN * 16);
    float*          counts  = pooled + GG * 32;

    const int propBlocks = (NN + 15) / 16;
    const int foldBlocks = ((NN + 15) / 16 + 3) / 4;

    zero_f<<<(GG * 33 + 255) / 256, 256, 0, stream>>>(pooled, GG * 33);
    precompute_small<<<10, 1024, 0, stream>>>(fW, fb, W1, b1, W2, b2, g1W, tab);
    mfrag_kernel<<<5, 256, 0, stream>>>(tab, Mfrag);

    bucket_hist<<<PBLK, 256, 0, stream>>>(ei, mat);
    scan_m1<<<MSB, 256, 0, stream>>>(mat, msum);
    scan_m2<<<1, 256, 0, stream>>>(msum);
    scan_m3<<<MSB, 256, 0, stream>>>(mat, msum);
    bucket_scatter<<<PBLK, 256, 0, stream>>>(ei, mat, part);
    bucket_build<<<NB, 256, 0, stream>>>(part, mat, x, csr_row, ideg, offs, dinv, xpad, xs);

    edgeconv_fused<<<2048, 256, 0, stream>>>(xs, offs, csr_row, tab, aggh);
    fold_mfma<<<foldBlocks, 256, 0, stream>>>(aggh, Mfrag, xpad, ideg, tab, g1W, y1);

    prop1_fused<<<propBlocks, 256, 0, stream>>>(offs, csr_row, (const unsigned int*)y1,
                                                dinv, g1b, g2W, y2p);
    prop2_plain<<<propBlocks, 256, 0, stream>>>(offs, csr_row, y2p, dinv, h2p);
    pool_seg<<<(NN + 511) / 512, 256, 0, stream>>>((const _Float16*)h2p, g2b, batch,
                                                   pooled, counts);
    final_kernel<<<1, 640, 0, stream>>>(pooled, counts, clsW, clsb, out);
}